// Round 8
// baseline (232.159 us; speedup 1.0000x reference)
//
#include <hip/hip_runtime.h>
#include <math.h>

#define BATCH 32768
#define DIM   256
#define NLAT  4096

typedef _Float16 f16x8 __attribute__((ext_vector_type(8)));
typedef float    f32x16 __attribute__((ext_vector_type(16)));

// ---------------------------------------------------------------------------
// ws byte offsets (total ~4.23 MB)
//   cbhf  : fp16 normalized codebook, FRAGMENT-MAJOR           2 MB
//           uint4 idx = frag*64 + lane,  frag = (t*16+sl)*2+rf
//           (lane = lh2*32 + row31 holds elements [16sl+8lh2 .. +8) of
//            code row t*64+rf*32+row31)
//   cbinv : float [4096]
//   keys  : uint [32768][16]  BIASED-FLOAT-PACKED (val|idx)    2 MB
//   hist  : int [4096]
// xhf (fp16 x, FRAGMENT-MAJOR, 16 MB) lives in the zq OUTPUT REGION as
// scratch (prep2 writes, vq_gemm reads, rescore overwrites with zq).
//   uint4 idx = (rowgrp*16 + sl)*64 + lhh*32 + (row&31),  rowgrp = row>>5
// psse (8192 doubles) reuses the cbhf region (dead after vq_gemm).
//
// KEY FORMAT: acc is biased +32.0 -> all values positive floats in (12,52)
// -> raw float bits are u32-ordered. key = (bits & 0xFFFFF000) | code(12b).
// kdec(key) = asfloat(key & 0xFFFFF000) (biased; rescore compares are
// relative so the bias cancels). Truncation err <= 0.0156 abs, within the
// 2*(3e-3*||x||) window budget (||x|| >= ~13 for chi2_256).
// ---------------------------------------------------------------------------
#define WS_CBH    0u
#define WS_CBINV  2097152u
#define WS_KEYS   2113536u
#define WS_HIST   4210688u

__device__ inline float kdec(uint key) {
  return __uint_as_float(key & 0xFFFFF000u);
}

// prep1: blocks [0,1024) compute cbinv (wave per codebook row);
// block 1024 zeros hist.
__global__ __launch_bounds__(256) void prep1_kernel(
    const float* __restrict__ cb, float* __restrict__ cbinv,
    int* __restrict__ hist) {
  int bid = blockIdx.x;
  if (bid < 1024) {
    int w = threadIdx.x >> 6, l = threadIdx.x & 63;
    int row = bid * 4 + w;
    const float4* cr = (const float4*)(cb + (size_t)row * DIM);
    float4 v = cr[l];
    float s = v.x * v.x + v.y * v.y + v.z * v.z + v.w * v.w;
    #pragma unroll
    for (int m = 32; m; m >>= 1) s += __shfl_xor(s, m, 64);
    if (l == 0) cbinv[row] = 1.0f / fmaxf(sqrtf(s), 1e-12f);
  } else {
    for (int k = threadIdx.x; k < NLAT; k += 256) hist[k] = 0;
  }
}

// prep2: ALL stores coalesced (thread <-> output index), reads are strided
// but consume full 64B lines. blocks [0,512): cbhf (normalized fp16,
// fragment-major); blocks [512,4608): xhf (fp16 x, fragment-major).
// (_Float16) rounding and the v*inv product are bit-identical to prior
// rounds -> downstream keys/argmax unchanged.
__global__ __launch_bounds__(256) void prep2_kernel(
    const float* __restrict__ x, const float* __restrict__ cb,
    const float* __restrict__ cbinv, uint4* __restrict__ cbhf4,
    uint4* __restrict__ xhf4) {
  int bid = blockIdx.x, tid = threadIdx.x;
  if (bid < 512) {
    int gid = bid * 256 + tid;             // uint4 out index, [0,131072)
    int frag = gid >> 6, lane = gid & 63;
    int rf = frag & 1, ts = frag >> 1, sl = ts & 15, t = ts >> 4;
    int row = t * 64 + rf * 32 + (lane & 31);
    int e4 = sl * 4 + (lane >> 5) * 2;     // float4 index within row
    const float4* cr = (const float4*)(cb + (size_t)row * DIM);
    float inv = cbinv[row];
    float4 a = cr[e4], b = cr[e4 + 1];
    union { _Float16 h[8]; uint4 u; } pk;
    pk.h[0] = (_Float16)(a.x * inv); pk.h[1] = (_Float16)(a.y * inv);
    pk.h[2] = (_Float16)(a.z * inv); pk.h[3] = (_Float16)(a.w * inv);
    pk.h[4] = (_Float16)(b.x * inv); pk.h[5] = (_Float16)(b.y * inv);
    pk.h[6] = (_Float16)(b.z * inv); pk.h[7] = (_Float16)(b.w * inv);
    cbhf4[gid] = pk.u;
  } else {
    int o = (bid - 512) * 256 + tid;       // uint4 out index, [0,1048576)
    int rowgrp = o >> 10, rem = o & 1023;
    int sl = rem >> 6, rem2 = rem & 63;
    int lhh = rem2 >> 5, l31r = rem2 & 31;
    int row = rowgrp * 32 + l31r;
    int c = sl * 2 + lhh;                  // 16B chunk within x row
    const float4* xs = (const float4*)x;
    float4 a = xs[(size_t)row * 64 + c * 2];
    float4 b = xs[(size_t)row * 64 + c * 2 + 1];
    union { _Float16 h[8]; uint4 u; } pk;
    pk.h[0] = (_Float16)a.x; pk.h[1] = (_Float16)a.y;
    pk.h[2] = (_Float16)a.z; pk.h[3] = (_Float16)a.w;
    pk.h[4] = (_Float16)b.x; pk.h[5] = (_Float16)b.y;
    pk.h[6] = (_Float16)b.z; pk.h[7] = (_Float16)b.w;
    xhf4[o] = pk.u;
  }
}

// MFMA GEMM (codes x batch) + per-row top-4 candidate keys.
// v7 (on v6's no-LDS frag-major stream):
//  - ring depth 4, prefetch distance 2 (16 % 4 == 0 -> slot indices stay
//    compile-time across the t loop)
//  - raw s_barrier per t: phase-locks the block's 4 waves so their
//    identical A-loads coalesce in L1 (cuts L2 re-reads ~4x). No data
//    crosses the barrier (each wave reads only its own registers) -- it
//    is purely a scheduling alignment device.
//  - s_setprio(1) around each MFMA pair
__global__ __launch_bounds__(256, 4) void vq_gemm_kernel(
    const char* __restrict__ xhf, const char* __restrict__ cbhf,
    uint* __restrict__ keys) {
  const int tid = threadIdx.x;
  const int w = tid >> 6, l = tid & 63;
  const int l31 = l & 31, lh = l >> 5;
  const int bb = blockIdx.x >> 2, q = blockIdx.x & 3;
  const int wrow0 = bb * 128 + w * 32;
  const int cbase = q * 1024;
  const uint lh4u = (uint)(lh << 2);

  // ---- x fragments (full K=256), coalesced 1KB loads ----
  const char* xb = xhf + ((size_t)(bb * 4 + w) * 1024 + l) * 16;
  f16x8 xf[16];
  #pragma unroll
  for (int s2 = 0; s2 < 16; ++s2) xf[s2] = *(const f16x8*)(xb + s2 * 1024);

  // ---- A-stream: linear walk, 4-slot ring, prefetch distance 2 ----
  const char* qbase = cbhf + (size_t)q * 524288 + (size_t)l * 16;
  f16x8 ring[4][2];
  #pragma unroll
  for (int s = 0; s < 2; ++s) {
    ring[s][0] = *(const f16x8*)(qbase + s * 2048);
    ring[s][1] = *(const f16x8*)(qbase + s * 2048 + 1024);
  }
  const char* pp = qbase + 4096;

  uint k1 = 0, k2 = 0, k3 = 0;   // packed top-3 (u32 order = value order)

  #pragma unroll 1
  for (int t = 0; t < 16; ++t) {
    __builtin_amdgcn_s_barrier();          // phase-lock 4 waves (L1 share)
    f32x16 acc[2];
    #pragma unroll
    for (int r = 0; r < 16; ++r) { acc[0][r] = 32.0f; acc[1][r] = 32.0f; }

    #pragma unroll
    for (int sl = 0; sl < 16; ++sl) {
      // prefetch stp = t*16+sl+2 into slot (sl+2)&3  (compile-time).
      // tail overruns <=4KB past the quarter into cbhf/cbinv: valid ws
      // memory, values never consumed.
      ring[(sl + 2) & 3][0] = *(const f16x8*)(pp);
      ring[(sl + 2) & 3][1] = *(const f16x8*)(pp + 1024);
      pp += 2048;
      __builtin_amdgcn_s_setprio(1);
      acc[0] = __builtin_amdgcn_mfma_f32_32x32x16_f16(
          ring[sl & 3][0], xf[sl], acc[0], 0, 0, 0);
      acc[1] = __builtin_amdgcn_mfma_f32_32x32x16_f16(
          ring[sl & 3][1], xf[sl], acc[1], 0, 0, 0);
      __builtin_amdgcn_s_setprio(0);
    }

    // branchless packed-key top-3 update (7 VALU/value, flat)
    const uint scode = (uint)(cbase + t * 64);
    #pragma unroll
    for (int rf = 0; rf < 2; ++rf) {
      #pragma unroll
      for (int r = 0; r < 16; ++r) {
        const uint cr = (uint)(rf * 32 + (r & 3) + 8 * (r >> 2));
        uint key = (__float_as_uint(acc[rf][r]) & 0xFFFFF000u)
                 | scode | cr | lh4u;
        uint m1 = max(k1, key), n1 = min(k1, key); k1 = m1;
        uint m2 = max(k2, n1),  n2 = min(k2, n1);  k2 = m2;
        k3 = max(k3, n2);
      }
    }
  }

  // ---- merge lane pair (l, l^32) -> top-4 keys, one uint4 store ----
  uint o1 = __shfl_xor(k1, 32, 64);
  uint o2 = __shfl_xor(k2, 32, 64);
  uint o3 = __shfl_xor(k3, 32, 64);
  uint k4 = 0;
  #pragma unroll
  for (int e = 0; e < 3; ++e) {
    uint o = (e == 0) ? o1 : (e == 1) ? o2 : o3;
    uint m = max(k1, o), n = min(k1, o); k1 = m;
    m = max(k2, n); n = min(k2, n); k2 = m;
    m = max(k3, n); n = min(k3, n); k3 = m;
    k4 = max(k4, n);
  }
  if (lh == 0) {
    uint4 kv; kv.x = k1; kv.y = k2; kv.z = k3; kv.w = k4;
    *(uint4*)(keys + (size_t)(wrow0 + l31) * 16 + q * 4) = kv;
  }
}

// Screened rescore: decode 16 candidate keys, exact-rescore only those
// within the rigorous error window; per-block SSE partial (no atomic).
__global__ __launch_bounds__(256) void rescore_kernel(
    const float* __restrict__ x, const float* __restrict__ cb,
    const float* __restrict__ cbinv, const uint* __restrict__ keys,
    float* __restrict__ zq, float* __restrict__ out_idx,
    int* __restrict__ hist, double* __restrict__ psse) {
  __shared__ float part[4];
  int tid = threadIdx.x, w = tid >> 6, l = tid & 63;
  int row = blockIdx.x * 4 + w;
  const float4* xr = (const float4*)(x + (size_t)row * DIM);
  float4 xv = xr[l];
  float s0 = xv.x * xv.x + xv.y * xv.y + xv.z * xv.z + xv.w * xv.w;
  #pragma unroll
  for (int m = 32; m; m >>= 1) s0 += __shfl_xor(s0, m, 64);
  float xnorm = sqrtf(s0);
  float xinv = 1.0f / fmaxf(xnorm, 1e-12f);

  uint key = keys[row * 16 + (l & 15)];
  uint kmax = key;
  #pragma unroll
  for (int m = 1; m < 16; m <<= 1) {
    uint o = __shfl_xor(kmax, m, 64);
    kmax = (o > kmax) ? o : kmax;
  }
  float dmax = kdec(kmax);   // biased by +32; compares below are relative
  float thr = dmax - 2.0f * (3e-3f * xnorm);
  bool inwin = (kdec(key) >= thr) && (l < 16);
  unsigned long long mask = __ballot(inwin);
  int besti;
  if (__popcll(mask) == 1) {
    besti = (int)(kmax & 0xFFFu);       // provably the exact argmax
  } else {
    float bestv = -3e38f; besti = 0x7fffffff;
    unsigned long long mm = mask;
    while (mm) {
      int b = __ffsll(mm) - 1; mm &= mm - 1;
      int ci = (int)(__shfl(key, b, 64) & 0xFFFu);
      float cbi = cbinv[ci];
      const float4* cr = (const float4*)(cb + (size_t)ci * DIM);
      float4 cv = cr[l];
      float d = (xv.x * xinv) * (cv.x * cbi) + (xv.y * xinv) * (cv.y * cbi)
              + (xv.z * xinv) * (cv.z * cbi) + (xv.w * xinv) * (cv.w * cbi);
      #pragma unroll
      for (int m = 32; m; m >>= 1) d += __shfl_xor(d, m, 64);
      bool better = (d > bestv) || (d == bestv && ci < besti);
      bestv = better ? d : bestv;
      besti = better ? ci : besti;
    }
  }

  float4 zv = ((const float4*)(cb + (size_t)besti * DIM))[l];
  float4 o;
  o.x = xv.x + (zv.x - xv.x); o.y = xv.y + (zv.y - xv.y);
  o.z = xv.z + (zv.z - xv.z); o.w = xv.w + (zv.w - xv.w);
  ((float4*)(zq + (size_t)row * DIM))[l] = o;
  float dx = xv.x - zv.x, dy = xv.y - zv.y, dz = xv.z - zv.z, dw = xv.w - zv.w;
  float s = dx * dx + dy * dy + dz * dz + dw * dw;
  #pragma unroll
  for (int m = 32; m; m >>= 1) s += __shfl_xor(s, m, 64);
  if (l == 0) part[w] = s;
  __syncthreads();
  if (tid == 0)
    psse[blockIdx.x] = (double)((part[0] + part[1]) + (part[2] + part[3]));
  if (l == 0) {
    atomicAdd(&hist[besti], 1);
    out_idx[row] = (float)besti;
  }
}

// Entropy from histogram + SSE partial reduction + final scalar losses.
__global__ __launch_bounds__(256) void finalize_kernel(
    const int* __restrict__ hist, const double* __restrict__ psse,
    float* __restrict__ outs) {
  int tid = threadIdx.x;
  double e = 0.0, s = 0.0;
  for (int k = tid; k < NLAT; k += 256) {
    int c = hist[k];
    if (c > 0) {
      float p = (float)c * (1.0f / 32768.0f);
      e += (double)(p * logf(p));
    }
  }
  for (int k = tid; k < BATCH / 4; k += 256) s += psse[k];
  #pragma unroll
  for (int off = 32; off; off >>= 1) {
    e += __shfl_xor(e, off, 64);
    s += __shfl_xor(s, off, 64);
  }
  __shared__ double pe[4], ps[4];
  int w = tid >> 6, l = tid & 63;
  if (l == 0) { pe[w] = e; ps[w] = s; }
  __syncthreads();
  if (tid == 0) {
    double H = -((pe[0] + pe[1]) + (pe[2] + pe[3]));
    double sse = (ps[0] + ps[1]) + (ps[2] + ps[3]);
    double qv = sse * (1.0 / ((double)BATCH * (double)DIM));
    float qf = (float)qv;
    float Hf = (float)H;
    float ent_loss = -Hf;
    float vq = qf + 0.25f * qf + 0.1f * ent_loss;
    outs[0] = vq;
    outs[1] = qf;
    outs[2] = qf;
    outs[3] = ent_loss;
    outs[4] = Hf;
  }
}

extern "C" void kernel_launch(void* const* d_in, const int* in_sizes, int n_in,
                              void* d_out, int out_size, void* d_ws, size_t ws_size,
                              hipStream_t stream) {
  const float* x  = (const float*)d_in[0];
  const float* cb = (const float*)d_in[1];

  float* out     = (float*)d_out;
  float* zq      = out;
  float* scalars = out + (size_t)BATCH * DIM;
  float* oidx    = scalars + 5;

  char* wsb = (char*)d_ws;
  ushort* cbhf  = (ushort*)(wsb + WS_CBH);
  float*  cbinv = (float*)(wsb + WS_CBINV);
  uint*   keys  = (uint*)(wsb + WS_KEYS);
  int*    hist  = (int*)(wsb + WS_HIST);
  // per-block SSE partials reuse the cbhf region (dead after vq_gemm)
  double* psse  = (double*)(wsb + WS_CBH);

  // fp16 fragment-major x scratch in the first 16 MB of the zq output
  ushort* xhf = (ushort*)d_out;

  prep1_kernel<<<1025, 256, 0, stream>>>(cb, cbinv, hist);
  prep2_kernel<<<4608, 256, 0, stream>>>(x, cb, cbinv,
                                         (uint4*)cbhf, (uint4*)xhf);
  vq_gemm_kernel<<<1024, 256, 0, stream>>>((const char*)xhf,
                                           (const char*)cbhf, keys);
  rescore_kernel<<<BATCH / 4, 256, 0, stream>>>(x, cb, cbinv, keys,
                                                zq, oidx, hist, psse);
  finalize_kernel<<<1, 256, 0, stream>>>(hist, psse, scalars);
}

// Round 9
// 201.568 us; speedup vs baseline: 1.1518x; 1.1518x over previous
//
#include <hip/hip_runtime.h>
#include <math.h>

#define BATCH 32768
#define DIM   256
#define NLAT  4096

typedef _Float16 f16x8 __attribute__((ext_vector_type(8)));
typedef float    f32x16 __attribute__((ext_vector_type(16)));

// ---------------------------------------------------------------------------
// ws byte offsets (total ~4.23 MB)
//   cbhf  : fp16 normalized codebook, FRAGMENT-MAJOR           2 MB
//           uint4 idx = frag*64 + lane,  frag = (t*16+sl)*2+rf
//   cbinv : float [4096]
//   keys  : uint [32768][16]  BIASED-FLOAT-PACKED (val|idx)    2 MB
//   hist  : int [4096]
// xhf (fp16 x, FRAGMENT-MAJOR, 16 MB) lives in the zq OUTPUT REGION as
// scratch (prep2 writes, vq_gemm reads, rescore overwrites with zq).
// psse (8192 doubles) reuses the cbhf region (dead after vq_gemm).
//
// KEY FORMAT: acc is biased +32.0 -> all values positive floats in (12,52)
// -> raw float bits are u32-ordered. key = (bits & 0xFFFFF000) | code(12b).
// kdec(key) = asfloat(key & 0xFFFFF000). Truncation err <= 0.0156 abs,
// within the 2*(3e-3*||x||) window budget (||x|| >= ~13 for chi2_256).
// ---------------------------------------------------------------------------
#define WS_CBH    0u
#define WS_CBINV  2097152u
#define WS_KEYS   2113536u
#define WS_HIST   4210688u

__device__ inline float kdec(uint key) {
  return __uint_as_float(key & 0xFFFFF000u);
}

// global -> LDS direct DMA, 16 B/lane (dest = WAVE-UNIFORM base; HW adds
// lane*16). Proven pattern from round 4.
__device__ inline void gload_lds16(const void* g, void* l) {
  __builtin_amdgcn_global_load_lds(
      (const __attribute__((address_space(1))) void*)g,
      (__attribute__((address_space(3))) void*)l, 16, 0, 0);
}

// prep1: blocks [0,1024) compute cbinv (wave per codebook row);
// block 1024 zeros hist.
__global__ __launch_bounds__(256) void prep1_kernel(
    const float* __restrict__ cb, float* __restrict__ cbinv,
    int* __restrict__ hist) {
  int bid = blockIdx.x;
  if (bid < 1024) {
    int w = threadIdx.x >> 6, l = threadIdx.x & 63;
    int row = bid * 4 + w;
    const float4* cr = (const float4*)(cb + (size_t)row * DIM);
    float4 v = cr[l];
    float s = v.x * v.x + v.y * v.y + v.z * v.z + v.w * v.w;
    #pragma unroll
    for (int m = 32; m; m >>= 1) s += __shfl_xor(s, m, 64);
    if (l == 0) cbinv[row] = 1.0f / fmaxf(sqrtf(s), 1e-12f);
  } else {
    for (int k = threadIdx.x; k < NLAT; k += 256) hist[k] = 0;
  }
}

// prep2: ALL stores coalesced; reads strided but consume full 64B lines.
// blocks [0,512): cbhf; blocks [512,4608): xhf. (_Float16) rounding
// bit-identical to prior rounds.
__global__ __launch_bounds__(256) void prep2_kernel(
    const float* __restrict__ x, const float* __restrict__ cb,
    const float* __restrict__ cbinv, uint4* __restrict__ cbhf4,
    uint4* __restrict__ xhf4) {
  int bid = blockIdx.x, tid = threadIdx.x;
  if (bid < 512) {
    int gid = bid * 256 + tid;             // uint4 out index, [0,131072)
    int frag = gid >> 6, lane = gid & 63;
    int rf = frag & 1, ts = frag >> 1, sl = ts & 15, t = ts >> 4;
    int row = t * 64 + rf * 32 + (lane & 31);
    int e4 = sl * 4 + (lane >> 5) * 2;     // float4 index within row
    const float4* cr = (const float4*)(cb + (size_t)row * DIM);
    float inv = cbinv[row];
    float4 a = cr[e4], b = cr[e4 + 1];
    union { _Float16 h[8]; uint4 u; } pk;
    pk.h[0] = (_Float16)(a.x * inv); pk.h[1] = (_Float16)(a.y * inv);
    pk.h[2] = (_Float16)(a.z * inv); pk.h[3] = (_Float16)(a.w * inv);
    pk.h[4] = (_Float16)(b.x * inv); pk.h[5] = (_Float16)(b.y * inv);
    pk.h[6] = (_Float16)(b.z * inv); pk.h[7] = (_Float16)(b.w * inv);
    cbhf4[gid] = pk.u;
  } else {
    int o = (bid - 512) * 256 + tid;       // uint4 out index, [0,1048576)
    int rowgrp = o >> 10, rem = o & 1023;
    int sl = rem >> 6, rem2 = rem & 63;
    int lhh = rem2 >> 5, l31r = rem2 & 31;
    int row = rowgrp * 32 + l31r;
    int c = sl * 2 + lhh;                  // 16B chunk within x row
    const float4* xs = (const float4*)x;
    float4 a = xs[(size_t)row * 64 + c * 2];
    float4 b = xs[(size_t)row * 64 + c * 2 + 1];
    union { _Float16 h[8]; uint4 u; } pk;
    pk.h[0] = (_Float16)a.x; pk.h[1] = (_Float16)a.y;
    pk.h[2] = (_Float16)a.z; pk.h[3] = (_Float16)a.w;
    pk.h[4] = (_Float16)b.x; pk.h[5] = (_Float16)b.y;
    pk.h[6] = (_Float16)b.z; pk.h[7] = (_Float16)b.w;
    xhf4[o] = pk.u;
  }
}

// MFMA GEMM (codes x batch) + per-row top-4 candidate keys.
// v9: LDS double-buffered DMA staging of the fragment-major A-tile.
//  - STAGE(t): 32 KB linear copy via global_load_lds (deep vmcnt queue
//    hides L2 latency -- the thing a VGPR ring cannot do)
//  - LDS image is fragment-major -> ds_read_b128 at frag*1024 + l*16 is
//    contiguous per wave: conflict-free, zero address math
//  - 2-phase: stage(t+1) issued before compute(t); ONE vmcnt(0)+barrier
//    per t. No s_barrier phase-lock, no setprio (R8 regression).
// grid 1024: bb = bid>>2 (256 rows/block, 32/wave), q = bid&3 (quarter).
__global__ __launch_bounds__(256, 2) void vq_gemm_kernel(
    const char* __restrict__ xhf, const char* __restrict__ cbhf,
    uint* __restrict__ keys) {
  __shared__ __align__(16) char smem[65536];

  const int tid = threadIdx.x;
  const int w = tid >> 6, l = tid & 63;
  const int l31 = l & 31, lh = l >> 5;
  const int bb = blockIdx.x >> 2, q = blockIdx.x & 3;
  const int wrow0 = bb * 128 + w * 32;
  const int cbase = q * 1024;
  const uint lh4u = (uint)(lh << 2);

  // ---- x fragments (full K=256), coalesced 1KB loads, resident ----
  const char* xb = xhf + ((size_t)(bb * 4 + w) * 1024 + l) * 16;
  f16x8 xf[16];
  #pragma unroll
  for (int s2 = 0; s2 < 16; ++s2) xf[s2] = *(const f16x8*)(xb + s2 * 1024);

  // ---- staging: tile t = 32 KB of fragment-major quarter, linear ----
  const char* qbase = cbhf + (size_t)q * 524288;
  auto STAGE = [&](int bufoff, int t) {
    const char* src = qbase + t * 32768 + (size_t)tid * 16;
    char* dst = smem + bufoff + w * 1024;      // wave-uniform; HW +lane*16
    #pragma unroll
    for (int s = 0; s < 8; ++s)
      gload_lds16(src + s * 4096, dst + s * 4096);
  };

  STAGE(0, 0);
  asm volatile("s_waitcnt vmcnt(0)" ::: "memory");
  __syncthreads();

  uint k1 = 0, k2 = 0, k3 = 0;   // packed top-3 (u32 order = value order)
  int curoff = 0;

  #pragma unroll 1
  for (int t = 0; t < 16; ++t) {
    if (t < 15) STAGE(curoff ^ 32768, t + 1);   // prefetch next tile

    f32x16 acc[2];
    #pragma unroll
    for (int r = 0; r < 16; ++r) { acc[0][r] = 32.0f; acc[1][r] = 32.0f; }

    const char* bp = smem + curoff + (size_t)l * 16;
    #pragma unroll
    for (int sl = 0; sl < 16; ++sl) {
      f16x8 a0 = *(const f16x8*)(bp + (sl * 2) * 1024);
      f16x8 a1 = *(const f16x8*)(bp + (sl * 2 + 1) * 1024);
      acc[0] = __builtin_amdgcn_mfma_f32_32x32x16_f16(
          a0, xf[sl], acc[0], 0, 0, 0);
      acc[1] = __builtin_amdgcn_mfma_f32_32x32x16_f16(
          a1, xf[sl], acc[1], 0, 0, 0);
    }

    // branchless packed-key top-3 update (7 VALU/value, flat)
    const uint scode = (uint)(cbase + t * 64);
    #pragma unroll
    for (int rf = 0; rf < 2; ++rf) {
      #pragma unroll
      for (int r = 0; r < 16; ++r) {
        const uint cr = (uint)(rf * 32 + (r & 3) + 8 * (r >> 2));
        uint key = (__float_as_uint(acc[rf][r]) & 0xFFFFF000u)
                 | scode | cr | lh4u;
        uint m1 = max(k1, key), n1 = min(k1, key); k1 = m1;
        uint m2 = max(k2, n1),  n2 = min(k2, n1);  k2 = m2;
        k3 = max(k3, n2);
      }
    }

    asm volatile("s_waitcnt vmcnt(0)" ::: "memory");  // t+1 loads landed
    __syncthreads();                                   // all waves done w/ bp
    curoff ^= 32768;
  }

  // ---- merge lane pair (l, l^32) -> top-4 keys, one uint4 store ----
  uint o1 = __shfl_xor(k1, 32, 64);
  uint o2 = __shfl_xor(k2, 32, 64);
  uint o3 = __shfl_xor(k3, 32, 64);
  uint k4 = 0;
  #pragma unroll
  for (int e = 0; e < 3; ++e) {
    uint o = (e == 0) ? o1 : (e == 1) ? o2 : o3;
    uint m = max(k1, o), n = min(k1, o); k1 = m;
    m = max(k2, n); n = min(k2, n); k2 = m;
    m = max(k3, n); n = min(k3, n); k3 = m;
    k4 = max(k4, n);
  }
  if (lh == 0) {
    uint4 kv; kv.x = k1; kv.y = k2; kv.z = k3; kv.w = k4;
    *(uint4*)(keys + (size_t)(wrow0 + l31) * 16 + q * 4) = kv;
  }
}

// Screened rescore: decode 16 candidate keys, exact-rescore only those
// within the rigorous error window; per-block SSE partial (no atomic).
__global__ __launch_bounds__(256) void rescore_kernel(
    const float* __restrict__ x, const float* __restrict__ cb,
    const float* __restrict__ cbinv, const uint* __restrict__ keys,
    float* __restrict__ zq, float* __restrict__ out_idx,
    int* __restrict__ hist, double* __restrict__ psse) {
  __shared__ float part[4];
  int tid = threadIdx.x, w = tid >> 6, l = tid & 63;
  int row = blockIdx.x * 4 + w;
  const float4* xr = (const float4*)(x + (size_t)row * DIM);
  float4 xv = xr[l];
  float s0 = xv.x * xv.x + xv.y * xv.y + xv.z * xv.z + xv.w * xv.w;
  #pragma unroll
  for (int m = 32; m; m >>= 1) s0 += __shfl_xor(s0, m, 64);
  float xnorm = sqrtf(s0);
  float xinv = 1.0f / fmaxf(xnorm, 1e-12f);

  uint key = keys[row * 16 + (l & 15)];
  uint kmax = key;
  #pragma unroll
  for (int m = 1; m < 16; m <<= 1) {
    uint o = __shfl_xor(kmax, m, 64);
    kmax = (o > kmax) ? o : kmax;
  }
  float dmax = kdec(kmax);   // biased by +32; compares below are relative
  float thr = dmax - 2.0f * (3e-3f * xnorm);
  bool inwin = (kdec(key) >= thr) && (l < 16);
  unsigned long long mask = __ballot(inwin);
  int besti;
  if (__popcll(mask) == 1) {
    besti = (int)(kmax & 0xFFFu);       // provably the exact argmax
  } else {
    float bestv = -3e38f; besti = 0x7fffffff;
    unsigned long long mm = mask;
    while (mm) {
      int b = __ffsll(mm) - 1; mm &= mm - 1;
      int ci = (int)(__shfl(key, b, 64) & 0xFFFu);
      float cbi = cbinv[ci];
      const float4* cr = (const float4*)(cb + (size_t)ci * DIM);
      float4 cv = cr[l];
      float d = (xv.x * xinv) * (cv.x * cbi) + (xv.y * xinv) * (cv.y * cbi)
              + (xv.z * xinv) * (cv.z * cbi) + (xv.w * xinv) * (cv.w * cbi);
      #pragma unroll
      for (int m = 32; m; m >>= 1) d += __shfl_xor(d, m, 64);
      bool better = (d > bestv) || (d == bestv && ci < besti);
      bestv = better ? d : bestv;
      besti = better ? ci : besti;
    }
  }

  float4 zv = ((const float4*)(cb + (size_t)besti * DIM))[l];
  float4 o;
  o.x = xv.x + (zv.x - xv.x); o.y = xv.y + (zv.y - xv.y);
  o.z = xv.z + (zv.z - xv.z); o.w = xv.w + (zv.w - xv.w);
  ((float4*)(zq + (size_t)row * DIM))[l] = o;
  float dx = xv.x - zv.x, dy = xv.y - zv.y, dz = xv.z - zv.z, dw = xv.w - zv.w;
  float s = dx * dx + dy * dy + dz * dz + dw * dw;
  #pragma unroll
  for (int m = 32; m; m >>= 1) s += __shfl_xor(s, m, 64);
  if (l == 0) part[w] = s;
  __syncthreads();
  if (tid == 0)
    psse[blockIdx.x] = (double)((part[0] + part[1]) + (part[2] + part[3]));
  if (l == 0) {
    atomicAdd(&hist[besti], 1);
    out_idx[row] = (float)besti;
  }
}

// Entropy from histogram + SSE partial reduction + final scalar losses.
__global__ __launch_bounds__(256) void finalize_kernel(
    const int* __restrict__ hist, const double* __restrict__ psse,
    float* __restrict__ outs) {
  int tid = threadIdx.x;
  double e = 0.0, s = 0.0;
  for (int k = tid; k < NLAT; k += 256) {
    int c = hist[k];
    if (c > 0) {
      float p = (float)c * (1.0f / 32768.0f);
      e += (double)(p * logf(p));
    }
  }
  for (int k = tid; k < BATCH / 4; k += 256) s += psse[k];
  #pragma unroll
  for (int off = 32; off; off >>= 1) {
    e += __shfl_xor(e, off, 64);
    s += __shfl_xor(s, off, 64);
  }
  __shared__ double pe[4], ps[4];
  int w = tid >> 6, l = tid & 63;
  if (l == 0) { pe[w] = e; ps[w] = s; }
  __syncthreads();
  if (tid == 0) {
    double H = -((pe[0] + pe[1]) + (pe[2] + pe[3]));
    double sse = (ps[0] + ps[1]) + (ps[2] + ps[3]);
    double qv = sse * (1.0 / ((double)BATCH * (double)DIM));
    float qf = (float)qv;
    float Hf = (float)H;
    float ent_loss = -Hf;
    float vq = qf + 0.25f * qf + 0.1f * ent_loss;
    outs[0] = vq;
    outs[1] = qf;
    outs[2] = qf;
    outs[3] = ent_loss;
    outs[4] = Hf;
  }
}

extern "C" void kernel_launch(void* const* d_in, const int* in_sizes, int n_in,
                              void* d_out, int out_size, void* d_ws, size_t ws_size,
                              hipStream_t stream) {
  const float* x  = (const float*)d_in[0];
  const float* cb = (const float*)d_in[1];

  float* out     = (float*)d_out;
  float* zq      = out;
  float* scalars = out + (size_t)BATCH * DIM;
  float* oidx    = scalars + 5;

  char* wsb = (char*)d_ws;
  ushort* cbhf  = (ushort*)(wsb + WS_CBH);
  float*  cbinv = (float*)(wsb + WS_CBINV);
  uint*   keys  = (uint*)(wsb + WS_KEYS);
  int*    hist  = (int*)(wsb + WS_HIST);
  // per-block SSE partials reuse the cbhf region (dead after vq_gemm)
  double* psse  = (double*)(wsb + WS_CBH);

  // fp16 fragment-major x scratch in the first 16 MB of the zq output
  ushort* xhf = (ushort*)d_out;

  prep1_kernel<<<1025, 256, 0, stream>>>(cb, cbinv, hist);
  prep2_kernel<<<4608, 256, 0, stream>>>(x, cb, cbinv,
                                         (uint4*)cbhf, (uint4*)xhf);
  vq_gemm_kernel<<<1024, 256, 0, stream>>>((const char*)xhf,
                                           (const char*)cbhf, keys);
  rescore_kernel<<<BATCH / 4, 256, 0, stream>>>(x, cb, cbinv, keys,
                                                zq, oidx, hist, psse);
  finalize_kernel<<<1, 256, 0, stream>>>(hist, psse, scalars);
}

// Round 10
// 200.840 us; speedup vs baseline: 1.1559x; 1.0036x over previous
//
#include <hip/hip_runtime.h>
#include <math.h>

#define BATCH 32768
#define DIM   256
#define NLAT  4096

typedef _Float16 f16x8 __attribute__((ext_vector_type(8)));
typedef float    f32x16 __attribute__((ext_vector_type(16)));

// ---------------------------------------------------------------------------
// ws byte offsets (total ~4.23 MB)
//   cbhf  : fp16 normalized codebook, FRAGMENT-MAJOR           2 MB
//           uint4 idx = frag*64 + lane,  frag = (t*16+sl)*2+rf
//   cbinv : float [4096]
//   keys  : uint [32768][16]  BIASED-FLOAT-PACKED (val|idx)    2 MB
//   hist  : int [4096]
// xhf (fp16 x, FRAGMENT-MAJOR, 16 MB) lives in the zq OUTPUT REGION as
// scratch (prep2 writes, vq_gemm reads, rescore overwrites with zq).
//   uint4 idx = (rowgrp*16 + sl)*64 + lhh*32 + (row&31),  rowgrp = row>>5
// psse (8192 doubles) reuses the cbhf region (dead after vq_gemm).
//
// KEY FORMAT: acc is biased +32.0 -> all values positive floats in (12,52)
// -> raw float bits are u32-ordered. key = (bits & 0xFFFFF000) | code(12b).
// kdec(key) = asfloat(key & 0xFFFFF000). Truncation err <= 0.0156 abs,
// within the 2*(3e-3*||x||) window budget (||x|| >= ~13 for chi2_256).
// ---------------------------------------------------------------------------
#define WS_CBH    0u
#define WS_CBINV  2097152u
#define WS_KEYS   2113536u
#define WS_HIST   4210688u

__device__ inline float kdec(uint key) {
  return __uint_as_float(key & 0xFFFFF000u);
}

// global -> LDS direct DMA, 16 B/lane (dest = WAVE-UNIFORM base; HW adds
// lane*16).
__device__ inline void gload_lds16(const void* g, void* l) {
  __builtin_amdgcn_global_load_lds(
      (const __attribute__((address_space(1))) void*)g,
      (__attribute__((address_space(3))) void*)l, 16, 0, 0);
}

// prep1: blocks [0,1024) compute cbinv (wave per codebook row);
// block 1024 zeros hist.
__global__ __launch_bounds__(256) void prep1_kernel(
    const float* __restrict__ cb, float* __restrict__ cbinv,
    int* __restrict__ hist) {
  int bid = blockIdx.x;
  if (bid < 1024) {
    int w = threadIdx.x >> 6, l = threadIdx.x & 63;
    int row = bid * 4 + w;
    const float4* cr = (const float4*)(cb + (size_t)row * DIM);
    float4 v = cr[l];
    float s = v.x * v.x + v.y * v.y + v.z * v.z + v.w * v.w;
    #pragma unroll
    for (int m = 32; m; m >>= 1) s += __shfl_xor(s, m, 64);
    if (l == 0) cbinv[row] = 1.0f / fmaxf(sqrtf(s), 1e-12f);
  } else {
    for (int k = threadIdx.x; k < NLAT; k += 256) hist[k] = 0;
  }
}

// prep2: ALL stores coalesced; reads strided but consume full 64B lines.
// blocks [0,512): cbhf; blocks [512,4608): xhf. (_Float16) rounding
// bit-identical to prior rounds.
__global__ __launch_bounds__(256) void prep2_kernel(
    const float* __restrict__ x, const float* __restrict__ cb,
    const float* __restrict__ cbinv, uint4* __restrict__ cbhf4,
    uint4* __restrict__ xhf4) {
  int bid = blockIdx.x, tid = threadIdx.x;
  if (bid < 512) {
    int gid = bid * 256 + tid;             // uint4 out index, [0,131072)
    int frag = gid >> 6, lane = gid & 63;
    int rf = frag & 1, ts = frag >> 1, sl = ts & 15, t = ts >> 4;
    int row = t * 64 + rf * 32 + (lane & 31);
    int e4 = sl * 4 + (lane >> 5) * 2;     // float4 index within row
    const float4* cr = (const float4*)(cb + (size_t)row * DIM);
    float inv = cbinv[row];
    float4 a = cr[e4], b = cr[e4 + 1];
    union { _Float16 h[8]; uint4 u; } pk;
    pk.h[0] = (_Float16)(a.x * inv); pk.h[1] = (_Float16)(a.y * inv);
    pk.h[2] = (_Float16)(a.z * inv); pk.h[3] = (_Float16)(a.w * inv);
    pk.h[4] = (_Float16)(b.x * inv); pk.h[5] = (_Float16)(b.y * inv);
    pk.h[6] = (_Float16)(b.z * inv); pk.h[7] = (_Float16)(b.w * inv);
    cbhf4[gid] = pk.u;
  } else {
    int o = (bid - 512) * 256 + tid;       // uint4 out index, [0,1048576)
    int rowgrp = o >> 10, rem = o & 1023;
    int sl = rem >> 6, rem2 = rem & 63;
    int lhh = rem2 >> 5, l31r = rem2 & 31;
    int row = rowgrp * 32 + l31r;
    int c = sl * 2 + lhh;                  // 16B chunk within x row
    const float4* xs = (const float4*)x;
    float4 a = xs[(size_t)row * 64 + c * 2];
    float4 b = xs[(size_t)row * 64 + c * 2 + 1];
    union { _Float16 h[8]; uint4 u; } pk;
    pk.h[0] = (_Float16)a.x; pk.h[1] = (_Float16)a.y;
    pk.h[2] = (_Float16)a.z; pk.h[3] = (_Float16)a.w;
    pk.h[4] = (_Float16)b.x; pk.h[5] = (_Float16)b.y;
    pk.h[6] = (_Float16)b.z; pk.h[7] = (_Float16)b.w;
    xhf4[o] = pk.u;
  }
}

// MFMA GEMM (codes x batch) + per-row top-4 candidate keys.
// v10 = v9 structure + A-READ AMORTIZATION: each wave owns 64 batch rows
// (2 row-groups fc), so each ds_read_b128 A-fragment feeds 2 MFMAs ->
// LDS-pipe load halves (41 -> 20.5 us/CU floor, below the 27.5 us MFMA
// floor). Wave count halves to 2048 = the 2 waves/SIMD we already run.
// grid 512: bb = bid>>2 (256 rows/block, 64/wave), q = bid&3 (quarter).
__global__ __launch_bounds__(256, 2) void vq_gemm_kernel(
    const char* __restrict__ xhf, const char* __restrict__ cbhf,
    uint* __restrict__ keys) {
  __shared__ __align__(16) char smem[65536];

  const int tid = threadIdx.x;
  const int w = tid >> 6, l = tid & 63;
  const int l31 = l & 31, lh = l >> 5;
  const int bb = blockIdx.x >> 2, q = blockIdx.x & 3;
  const int wrow0 = bb * 256 + w * 64;
  const int cbase = q * 1024;
  const uint lh4u = (uint)(lh << 2);

  // ---- x fragments: 2 row-groups x 16 sl, coalesced 1KB loads ----
  f16x8 xf[16][2];
  #pragma unroll
  for (int fc = 0; fc < 2; ++fc) {
    const char* xb = xhf + (size_t)(bb * 8 + w * 2 + fc) * 16384
                   + (size_t)l * 16;
    #pragma unroll
    for (int s2 = 0; s2 < 16; ++s2)
      xf[s2][fc] = *(const f16x8*)(xb + s2 * 1024);
  }

  // ---- staging: tile t = 32 KB of fragment-major quarter, linear ----
  const char* qbase = cbhf + (size_t)q * 524288;
  auto STAGE = [&](int bufoff, int t) {
    const char* src = qbase + t * 32768 + (size_t)tid * 16;
    char* dst = smem + bufoff + w * 1024;      // wave-uniform; HW +lane*16
    #pragma unroll
    for (int s = 0; s < 8; ++s)
      gload_lds16(src + s * 4096, dst + s * 4096);
  };

  STAGE(0, 0);
  asm volatile("s_waitcnt vmcnt(0)" ::: "memory");
  __syncthreads();

  uint k1[2] = {0, 0}, k2[2] = {0, 0}, k3[2] = {0, 0};
  int curoff = 0;

  #pragma unroll 1
  for (int t = 0; t < 16; ++t) {
    if (t < 15) STAGE(curoff ^ 32768, t + 1);   // prefetch next tile

    f32x16 acc[2][2];                           // [rf][fc]
    #pragma unroll
    for (int rf = 0; rf < 2; ++rf)
      #pragma unroll
      for (int fc = 0; fc < 2; ++fc)
        #pragma unroll
        for (int r = 0; r < 16; ++r) acc[rf][fc][r] = 32.0f;

    const char* bp = smem + curoff + (size_t)l * 16;
    #pragma unroll
    for (int sl = 0; sl < 16; ++sl) {
      f16x8 a0 = *(const f16x8*)(bp + (sl * 2) * 1024);
      f16x8 a1 = *(const f16x8*)(bp + (sl * 2 + 1) * 1024);
      #pragma unroll
      for (int fc = 0; fc < 2; ++fc) {
        acc[0][fc] = __builtin_amdgcn_mfma_f32_32x32x16_f16(
            a0, xf[sl][fc], acc[0][fc], 0, 0, 0);
        acc[1][fc] = __builtin_amdgcn_mfma_f32_32x32x16_f16(
            a1, xf[sl][fc], acc[1][fc], 0, 0, 0);
      }
    }

    // branchless packed-key top-3 update per row-group (7 VALU/value)
    const uint scode = (uint)(cbase + t * 64);
    #pragma unroll
    for (int fc = 0; fc < 2; ++fc) {
      #pragma unroll
      for (int rf = 0; rf < 2; ++rf) {
        #pragma unroll
        for (int r = 0; r < 16; ++r) {
          const uint cr = (uint)(rf * 32 + (r & 3) + 8 * (r >> 2));
          uint key = (__float_as_uint(acc[rf][fc][r]) & 0xFFFFF000u)
                   | scode | cr | lh4u;
          uint m1 = max(k1[fc], key), n1 = min(k1[fc], key); k1[fc] = m1;
          uint m2 = max(k2[fc], n1),  n2 = min(k2[fc], n1);  k2[fc] = m2;
          k3[fc] = max(k3[fc], n2);
        }
      }
    }

    asm volatile("s_waitcnt vmcnt(0)" ::: "memory");  // t+1 loads landed
    __syncthreads();                                   // all waves done w/ bp
    curoff ^= 32768;
  }

  // ---- merge lane pair (l, l^32) -> top-4 keys per row-group ----
  #pragma unroll
  for (int fc = 0; fc < 2; ++fc) {
    uint a1 = k1[fc], a2 = k2[fc], a3 = k3[fc];
    uint o1 = __shfl_xor(a1, 32, 64);
    uint o2 = __shfl_xor(a2, 32, 64);
    uint o3 = __shfl_xor(a3, 32, 64);
    uint a4 = 0;
    #pragma unroll
    for (int e = 0; e < 3; ++e) {
      uint o = (e == 0) ? o1 : (e == 1) ? o2 : o3;
      uint m = max(a1, o), n = min(a1, o); a1 = m;
      m = max(a2, n); n = min(a2, n); a2 = m;
      m = max(a3, n); n = min(a3, n); a3 = m;
      a4 = max(a4, n);
    }
    if (lh == 0) {
      uint4 kv; kv.x = a1; kv.y = a2; kv.z = a3; kv.w = a4;
      *(uint4*)(keys + (size_t)(wrow0 + fc * 32 + l31) * 16 + q * 4) = kv;
    }
  }
}

// Screened rescore: decode 16 candidate keys, exact-rescore only those
// within the rigorous error window; per-block SSE partial (no atomic).
__global__ __launch_bounds__(256) void rescore_kernel(
    const float* __restrict__ x, const float* __restrict__ cb,
    const float* __restrict__ cbinv, const uint* __restrict__ keys,
    float* __restrict__ zq, float* __restrict__ out_idx,
    int* __restrict__ hist, double* __restrict__ psse) {
  __shared__ float part[4];
  int tid = threadIdx.x, w = tid >> 6, l = tid & 63;
  int row = blockIdx.x * 4 + w;
  const float4* xr = (const float4*)(x + (size_t)row * DIM);
  float4 xv = xr[l];
  float s0 = xv.x * xv.x + xv.y * xv.y + xv.z * xv.z + xv.w * xv.w;
  #pragma unroll
  for (int m = 32; m; m >>= 1) s0 += __shfl_xor(s0, m, 64);
  float xnorm = sqrtf(s0);
  float xinv = 1.0f / fmaxf(xnorm, 1e-12f);

  uint key = keys[row * 16 + (l & 15)];
  uint kmax = key;
  #pragma unroll
  for (int m = 1; m < 16; m <<= 1) {
    uint o = __shfl_xor(kmax, m, 64);
    kmax = (o > kmax) ? o : kmax;
  }
  float dmax = kdec(kmax);   // biased by +32; compares below are relative
  float thr = dmax - 2.0f * (3e-3f * xnorm);
  bool inwin = (kdec(key) >= thr) && (l < 16);
  unsigned long long mask = __ballot(inwin);
  int besti;
  if (__popcll(mask) == 1) {
    besti = (int)(kmax & 0xFFFu);       // provably the exact argmax
  } else {
    float bestv = -3e38f; besti = 0x7fffffff;
    unsigned long long mm = mask;
    while (mm) {
      int b = __ffsll(mm) - 1; mm &= mm - 1;
      int ci = (int)(__shfl(key, b, 64) & 0xFFFu);
      float cbi = cbinv[ci];
      const float4* cr = (const float4*)(cb + (size_t)ci * DIM);
      float4 cv = cr[l];
      float d = (xv.x * xinv) * (cv.x * cbi) + (xv.y * xinv) * (cv.y * cbi)
              + (xv.z * xinv) * (cv.z * cbi) + (xv.w * xinv) * (cv.w * cbi);
      #pragma unroll
      for (int m = 32; m; m >>= 1) d += __shfl_xor(d, m, 64);
      bool better = (d > bestv) || (d == bestv && ci < besti);
      bestv = better ? d : bestv;
      besti = better ? ci : besti;
    }
  }

  float4 zv = ((const float4*)(cb + (size_t)besti * DIM))[l];
  float4 o;
  o.x = xv.x + (zv.x - xv.x); o.y = xv.y + (zv.y - xv.y);
  o.z = xv.z + (zv.z - xv.z); o.w = xv.w + (zv.w - xv.w);
  ((float4*)(zq + (size_t)row * DIM))[l] = o;
  float dx = xv.x - zv.x, dy = xv.y - zv.y, dz = xv.z - zv.z, dw = xv.w - zv.w;
  float s = dx * dx + dy * dy + dz * dz + dw * dw;
  #pragma unroll
  for (int m = 32; m; m >>= 1) s += __shfl_xor(s, m, 64);
  if (l == 0) part[w] = s;
  __syncthreads();
  if (tid == 0)
    psse[blockIdx.x] = (double)((part[0] + part[1]) + (part[2] + part[3]));
  if (l == 0) {
    atomicAdd(&hist[besti], 1);
    out_idx[row] = (float)besti;
  }
}

// Entropy from histogram + SSE partial reduction + final scalar losses.
__global__ __launch_bounds__(256) void finalize_kernel(
    const int* __restrict__ hist, const double* __restrict__ psse,
    float* __restrict__ outs) {
  int tid = threadIdx.x;
  double e = 0.0, s = 0.0;
  for (int k = tid; k < NLAT; k += 256) {
    int c = hist[k];
    if (c > 0) {
      float p = (float)c * (1.0f / 32768.0f);
      e += (double)(p * logf(p));
    }
  }
  for (int k = tid; k < BATCH / 4; k += 256) s += psse[k];
  #pragma unroll
  for (int off = 32; off; off >>= 1) {
    e += __shfl_xor(e, off, 64);
    s += __shfl_xor(s, off, 64);
  }
  __shared__ double pe[4], ps[4];
  int w = tid >> 6, l = tid & 63;
  if (l == 0) { pe[w] = e; ps[w] = s; }
  __syncthreads();
  if (tid == 0) {
    double H = -((pe[0] + pe[1]) + (pe[2] + pe[3]));
    double sse = (ps[0] + ps[1]) + (ps[2] + ps[3]);
    double qv = sse * (1.0 / ((double)BATCH * (double)DIM));
    float qf = (float)qv;
    float Hf = (float)H;
    float ent_loss = -Hf;
    float vq = qf + 0.25f * qf + 0.1f * ent_loss;
    outs[0] = vq;
    outs[1] = qf;
    outs[2] = qf;
    outs[3] = ent_loss;
    outs[4] = Hf;
  }
}

extern "C" void kernel_launch(void* const* d_in, const int* in_sizes, int n_in,
                              void* d_out, int out_size, void* d_ws, size_t ws_size,
                              hipStream_t stream) {
  const float* x  = (const float*)d_in[0];
  const float* cb = (const float*)d_in[1];

  float* out     = (float*)d_out;
  float* zq      = out;
  float* scalars = out + (size_t)BATCH * DIM;
  float* oidx    = scalars + 5;

  char* wsb = (char*)d_ws;
  ushort* cbhf  = (ushort*)(wsb + WS_CBH);
  float*  cbinv = (float*)(wsb + WS_CBINV);
  uint*   keys  = (uint*)(wsb + WS_KEYS);
  int*    hist  = (int*)(wsb + WS_HIST);
  // per-block SSE partials reuse the cbhf region (dead after vq_gemm)
  double* psse  = (double*)(wsb + WS_CBH);

  // fp16 fragment-major x scratch in the first 16 MB of the zq output
  ushort* xhf = (ushort*)d_out;

  prep1_kernel<<<1025, 256, 0, stream>>>(cb, cbinv, hist);
  prep2_kernel<<<4608, 256, 0, stream>>>(x, cb, cbinv,
                                         (uint4*)cbhf, (uint4*)xhf);
  vq_gemm_kernel<<<512, 256, 0, stream>>>((const char*)xhf,
                                          (const char*)cbhf, keys);
  rescore_kernel<<<BATCH / 4, 256, 0, stream>>>(x, cb, cbinv, keys,
                                                zq, oidx, hist, psse);
  finalize_kernel<<<1, 256, 0, stream>>>(hist, psse, scalars);
}

// Round 11
// 200.590 us; speedup vs baseline: 1.1574x; 1.0012x over previous
//
#include <hip/hip_runtime.h>
#include <math.h>

#define BATCH 32768
#define DIM   256
#define NLAT  4096

typedef _Float16 f16x8 __attribute__((ext_vector_type(8)));
typedef float    f32x16 __attribute__((ext_vector_type(16)));

// ---------------------------------------------------------------------------
// ws byte offsets (total ~4.23 MB)
//   cbhf  : fp16 normalized codebook, FRAGMENT-MAJOR           2 MB
//           uint4 idx = frag*64 + lane,  frag = (t*16+sl)*2+rf
//   cbinv : float [4096]
//   keys  : uint [32768][16]  BIASED-FLOAT-PACKED (val|idx)    2 MB
//   hist  : int [4096]
// xhf (fp16 x, FRAGMENT-MAJOR, 16 MB) lives in the zq OUTPUT REGION as
// scratch (prep2 writes, vq_gemm reads, rescore overwrites with zq).
//   uint4 idx = (rowgrp*16 + sl)*64 + lhh*32 + (row&31),  rowgrp = row>>5
// psse (8192 doubles) reuses the cbhf region (dead after vq_gemm).
//
// KEY FORMAT: acc is biased +32.0 -> all values positive floats in (12,52)
// -> raw float bits are u32-ordered. key = (bits & 0xFFFFF000) | code(12b).
// kdec(key) = asfloat(key & 0xFFFFF000). Truncation err <= 0.0156 abs,
// within the 2*(3e-3*||x||) window budget (||x|| >= ~13 for chi2_256).
// ---------------------------------------------------------------------------
#define WS_CBH    0u
#define WS_CBINV  2097152u
#define WS_KEYS   2113536u
#define WS_HIST   4210688u

__device__ inline float kdec(uint key) {
  return __uint_as_float(key & 0xFFFFF000u);
}

// global -> LDS direct DMA, 16 B/lane (dest = WAVE-UNIFORM base; HW adds
// lane*16).
__device__ inline void gload_lds16(const void* g, void* l) {
  __builtin_amdgcn_global_load_lds(
      (const __attribute__((address_space(1))) void*)g,
      (__attribute__((address_space(3))) void*)l, 16, 0, 0);
}

// prep1: blocks [0,1024) compute cbinv (wave per codebook row);
// block 1024 zeros hist.
__global__ __launch_bounds__(256) void prep1_kernel(
    const float* __restrict__ cb, float* __restrict__ cbinv,
    int* __restrict__ hist) {
  int bid = blockIdx.x;
  if (bid < 1024) {
    int w = threadIdx.x >> 6, l = threadIdx.x & 63;
    int row = bid * 4 + w;
    const float4* cr = (const float4*)(cb + (size_t)row * DIM);
    float4 v = cr[l];
    float s = v.x * v.x + v.y * v.y + v.z * v.z + v.w * v.w;
    #pragma unroll
    for (int m = 32; m; m >>= 1) s += __shfl_xor(s, m, 64);
    if (l == 0) cbinv[row] = 1.0f / fmaxf(sqrtf(s), 1e-12f);
  } else {
    for (int k = threadIdx.x; k < NLAT; k += 256) hist[k] = 0;
  }
}

// prep2 v11: x-path via LDS transpose -- reads AND writes fully coalesced
// (was: 32B reads at 1KB stride). blocks [0,1024): one 32-row group each;
// blocks [1024,1536): cbhf (unchanged mapping, small). (_Float16) rounding
// bit-identical to prior rounds -> downstream keys/argmax unchanged.
__global__ __launch_bounds__(256) void prep2_kernel(
    const float* __restrict__ x, const float* __restrict__ cb,
    const float* __restrict__ cbinv, uint4* __restrict__ cbhf4,
    uint4* __restrict__ xhf4) {
  int bid = blockIdx.x, tid = threadIdx.x;
  if (bid < 1024) {
    __shared__ __align__(16) uint4 lds[1024];          // 16 KB
    const float4* xs = (const float4*)x + (size_t)bid * 2048;
    #pragma unroll
    for (int k = 0; k < 4; ++k) {
      int g = tid * 4 + k;              // chunk: row31 = g>>5, c = g&31
      float4 a = xs[g * 2];
      float4 b = xs[g * 2 + 1];         // 128B contiguous per thread
      union { _Float16 h[8]; uint4 u; } pk;
      pk.h[0] = (_Float16)a.x; pk.h[1] = (_Float16)a.y;
      pk.h[2] = (_Float16)a.z; pk.h[3] = (_Float16)a.w;
      pk.h[4] = (_Float16)b.x; pk.h[5] = (_Float16)b.y;
      pk.h[6] = (_Float16)b.z; pk.h[7] = (_Float16)b.w;
      int row31 = g >> 5, c = g & 31;
      lds[(c >> 1) * 64 + (c & 1) * 32 + row31] = pk.u;
    }
    __syncthreads();
    uint4* outp = xhf4 + (size_t)bid * 1024;
    #pragma unroll
    for (int k = 0; k < 4; ++k)
      outp[tid * 4 + k] = lds[tid * 4 + k];            // 64B/thread
  } else {
    int gid = (bid - 1024) * 256 + tid;    // uint4 out index, [0,131072)
    int frag = gid >> 6, lane = gid & 63;
    int rf = frag & 1, ts = frag >> 1, sl = ts & 15, t = ts >> 4;
    int row = t * 64 + rf * 32 + (lane & 31);
    int e4 = sl * 4 + (lane >> 5) * 2;     // float4 index within row
    const float4* cr = (const float4*)(cb + (size_t)row * DIM);
    float inv = cbinv[row];
    float4 a = cr[e4], b = cr[e4 + 1];
    union { _Float16 h[8]; uint4 u; } pk;
    pk.h[0] = (_Float16)(a.x * inv); pk.h[1] = (_Float16)(a.y * inv);
    pk.h[2] = (_Float16)(a.z * inv); pk.h[3] = (_Float16)(a.w * inv);
    pk.h[4] = (_Float16)(b.x * inv); pk.h[5] = (_Float16)(b.y * inv);
    pk.h[6] = (_Float16)(b.z * inv); pk.h[7] = (_Float16)(b.w * inv);
    cbhf4[gid] = pk.u;
  }
}

// MFMA GEMM (codes x batch) + per-row top-4 candidate keys.
// v11 = v10 + COUNTED-VMCNT PHASE PIPELINE (T3+T4+T5):
//  - 4 x 16KB half-tile LDS buffers; half-tile h in [0,32), buffer h&3
//  - each phase: {STAGE(h+3) [4 loads]; vmcnt(12); barrier; compute(h);
//    barrier}. vmcnt NEVER drains to 0 in the loop: 12 loads (3 half-
//    tiles) stay in flight across every barrier.
//  - tail STAGE wraps (h+3)&31 into buffers that are provably dead
//    (race-checked: last read completed before the preceding barrier).
//  - s_setprio(1) around each ds_read+MFMA cluster (phase-split -> T5).
// grid 512: bb = bid>>2 (256 rows/block, 64/wave), q = bid&3 (quarter).
__global__ __launch_bounds__(256, 2) void vq_gemm_kernel(
    const char* __restrict__ xhf, const char* __restrict__ cbhf,
    uint* __restrict__ keys) {
  __shared__ __align__(16) char smem[65536];   // 4 x 16KB

  const int tid = threadIdx.x;
  const int w = tid >> 6, l = tid & 63;
  const int l31 = l & 31, lh = l >> 5;
  const int bb = blockIdx.x >> 2, q = blockIdx.x & 3;
  const int wrow0 = bb * 256 + w * 64;
  const int cbase = q * 1024;
  const uint lh4u = (uint)(lh << 2);

  // ---- x fragments: 2 row-groups x 16 sl, coalesced 1KB loads ----
  f16x8 xf[16][2];
  #pragma unroll
  for (int fc = 0; fc < 2; ++fc) {
    const char* xb = xhf + (size_t)(bb * 8 + w * 2 + fc) * 16384
                   + (size_t)l * 16;
    #pragma unroll
    for (int s2 = 0; s2 < 16; ++s2)
      xf[s2][fc] = *(const f16x8*)(xb + s2 * 1024);
  }

  const char* qbase = cbhf + (size_t)q * 524288;
  // STAGE half-tile h (16 KB): 4 gload_lds16/thread into buffer h&3
  auto STAGE = [&](int h) {
    const char* src = qbase + h * 16384 + (size_t)tid * 16;
    char* dst = smem + (h & 3) * 16384 + w * 1024;   // wave-uniform base
    #pragma unroll
    for (int s = 0; s < 4; ++s)
      gload_lds16(src + s * 4096, dst + s * 4096);
  };

  // clean vmcnt baseline: xf loads drained before staging begins
  asm volatile("s_waitcnt vmcnt(0)" ::: "memory");
  STAGE(0); STAGE(1); STAGE(2);

  uint k1[2] = {0, 0}, k2[2] = {0, 0}, k3[2] = {0, 0};

  #pragma unroll 1
  for (int t = 0; t < 16; ++t) {
    f32x16 acc[2][2];                           // [rf][fc]

    // ---- phase A: half-tile h = 2t (sl 0..7) ----
    STAGE((2 * t + 3) & 31);
    asm volatile("s_waitcnt vmcnt(12)" ::: "memory");  // h's 4 loads done
    __syncthreads();                                   // visible to all
    #pragma unroll
    for (int rf = 0; rf < 2; ++rf)
      #pragma unroll
      for (int fc = 0; fc < 2; ++fc)
        #pragma unroll
        for (int r = 0; r < 16; ++r) acc[rf][fc][r] = 32.0f;
    {
      const char* bp = smem + ((2 * t) & 3) * 16384 + (size_t)l * 16;
      __builtin_amdgcn_s_setprio(1);
      #pragma unroll
      for (int s8 = 0; s8 < 8; ++s8) {
        f16x8 a0 = *(const f16x8*)(bp + s8 * 2048);
        f16x8 a1 = *(const f16x8*)(bp + s8 * 2048 + 1024);
        #pragma unroll
        for (int fc = 0; fc < 2; ++fc) {
          acc[0][fc] = __builtin_amdgcn_mfma_f32_32x32x16_f16(
              a0, xf[s8][fc], acc[0][fc], 0, 0, 0);
          acc[1][fc] = __builtin_amdgcn_mfma_f32_32x32x16_f16(
              a1, xf[s8][fc], acc[1][fc], 0, 0, 0);
        }
      }
      __builtin_amdgcn_s_setprio(0);
    }
    __syncthreads();            // all waves done reading buf (2t)&3

    // ---- phase B: half-tile h = 2t+1 (sl 8..15) ----
    STAGE((2 * t + 4) & 31);
    asm volatile("s_waitcnt vmcnt(12)" ::: "memory");
    __syncthreads();
    {
      const char* bp = smem + ((2 * t + 1) & 3) * 16384 + (size_t)l * 16;
      __builtin_amdgcn_s_setprio(1);
      #pragma unroll
      for (int s8 = 0; s8 < 8; ++s8) {
        f16x8 a0 = *(const f16x8*)(bp + s8 * 2048);
        f16x8 a1 = *(const f16x8*)(bp + s8 * 2048 + 1024);
        #pragma unroll
        for (int fc = 0; fc < 2; ++fc) {
          acc[0][fc] = __builtin_amdgcn_mfma_f32_32x32x16_f16(
              a0, xf[8 + s8][fc], acc[0][fc], 0, 0, 0);
          acc[1][fc] = __builtin_amdgcn_mfma_f32_32x32x16_f16(
              a1, xf[8 + s8][fc], acc[1][fc], 0, 0, 0);
        }
      }
      __builtin_amdgcn_s_setprio(0);
    }

    // branchless packed-key top-3 update per row-group (registers only)
    const uint scode = (uint)(cbase + t * 64);
    #pragma unroll
    for (int fc = 0; fc < 2; ++fc) {
      #pragma unroll
      for (int rf = 0; rf < 2; ++rf) {
        #pragma unroll
        for (int r = 0; r < 16; ++r) {
          const uint cr = (uint)(rf * 32 + (r & 3) + 8 * (r >> 2));
          uint key = (__float_as_uint(acc[rf][fc][r]) & 0xFFFFF000u)
                   | scode | cr | lh4u;
          uint m1 = max(k1[fc], key), n1 = min(k1[fc], key); k1[fc] = m1;
          uint m2 = max(k2[fc], n1),  n2 = min(k2[fc], n1);  k2[fc] = m2;
          k3[fc] = max(k3[fc], n2);
        }
      }
    }
    __syncthreads();            // all waves done reading buf (2t+1)&3
  }
  asm volatile("s_waitcnt vmcnt(0)" ::: "memory");  // drain wrapped tail

  // ---- merge lane pair (l, l^32) -> top-4 keys per row-group ----
  #pragma unroll
  for (int fc = 0; fc < 2; ++fc) {
    uint a1 = k1[fc], a2 = k2[fc], a3 = k3[fc];
    uint o1 = __shfl_xor(a1, 32, 64);
    uint o2 = __shfl_xor(a2, 32, 64);
    uint o3 = __shfl_xor(a3, 32, 64);
    uint a4 = 0;
    #pragma unroll
    for (int e = 0; e < 3; ++e) {
      uint o = (e == 0) ? o1 : (e == 1) ? o2 : o3;
      uint m = max(a1, o), n = min(a1, o); a1 = m;
      m = max(a2, n); n = min(a2, n); a2 = m;
      m = max(a3, n); n = min(a3, n); a3 = m;
      a4 = max(a4, n);
    }
    if (lh == 0) {
      uint4 kv; kv.x = a1; kv.y = a2; kv.z = a3; kv.w = a4;
      *(uint4*)(keys + (size_t)(wrow0 + fc * 32 + l31) * 16 + q * 4) = kv;
    }
  }
}

// Screened rescore: decode 16 candidate keys, exact-rescore only those
// within the rigorous error window; per-block SSE partial (no atomic).
__global__ __launch_bounds__(256) void rescore_kernel(
    const float* __restrict__ x, const float* __restrict__ cb,
    const float* __restrict__ cbinv, const uint* __restrict__ keys,
    float* __restrict__ zq, float* __restrict__ out_idx,
    int* __restrict__ hist, double* __restrict__ psse) {
  __shared__ float part[4];
  int tid = threadIdx.x, w = tid >> 6, l = tid & 63;
  int row = blockIdx.x * 4 + w;
  const float4* xr = (const float4*)(x + (size_t)row * DIM);
  float4 xv = xr[l];
  float s0 = xv.x * xv.x + xv.y * xv.y + xv.z * xv.z + xv.w * xv.w;
  #pragma unroll
  for (int m = 32; m; m >>= 1) s0 += __shfl_xor(s0, m, 64);
  float xnorm = sqrtf(s0);
  float xinv = 1.0f / fmaxf(xnorm, 1e-12f);

  uint key = keys[row * 16 + (l & 15)];
  uint kmax = key;
  #pragma unroll
  for (int m = 1; m < 16; m <<= 1) {
    uint o = __shfl_xor(kmax, m, 64);
    kmax = (o > kmax) ? o : kmax;
  }
  float dmax = kdec(kmax);   // biased by +32; compares below are relative
  float thr = dmax - 2.0f * (3e-3f * xnorm);
  bool inwin = (kdec(key) >= thr) && (l < 16);
  unsigned long long mask = __ballot(inwin);
  int besti;
  if (__popcll(mask) == 1) {
    besti = (int)(kmax & 0xFFFu);       // provably the exact argmax
  } else {
    float bestv = -3e38f; besti = 0x7fffffff;
    unsigned long long mm = mask;
    while (mm) {
      int b = __ffsll(mm) - 1; mm &= mm - 1;
      int ci = (int)(__shfl(key, b, 64) & 0xFFFu);
      float cbi = cbinv[ci];
      const float4* cr = (const float4*)(cb + (size_t)ci * DIM);
      float4 cv = cr[l];
      float d = (xv.x * xinv) * (cv.x * cbi) + (xv.y * xinv) * (cv.y * cbi)
              + (xv.z * xinv) * (cv.z * cbi) + (xv.w * xinv) * (cv.w * cbi);
      #pragma unroll
      for (int m = 32; m; m >>= 1) d += __shfl_xor(d, m, 64);
      bool better = (d > bestv) || (d == bestv && ci < besti);
      bestv = better ? d : bestv;
      besti = better ? ci : besti;
    }
  }

  float4 zv = ((const float4*)(cb + (size_t)besti * DIM))[l];
  float4 o;
  o.x = xv.x + (zv.x - xv.x); o.y = xv.y + (zv.y - xv.y);
  o.z = xv.z + (zv.z - xv.z); o.w = xv.w + (zv.w - xv.w);
  ((float4*)(zq + (size_t)row * DIM))[l] = o;
  float dx = xv.x - zv.x, dy = xv.y - zv.y, dz = xv.z - zv.z, dw = xv.w - zv.w;
  float s = dx * dx + dy * dy + dz * dz + dw * dw;
  #pragma unroll
  for (int m = 32; m; m >>= 1) s += __shfl_xor(s, m, 64);
  if (l == 0) part[w] = s;
  __syncthreads();
  if (tid == 0)
    psse[blockIdx.x] = (double)((part[0] + part[1]) + (part[2] + part[3]));
  if (l == 0) {
    atomicAdd(&hist[besti], 1);
    out_idx[row] = (float)besti;
  }
}

// Entropy from histogram + SSE partial reduction + final scalar losses.
__global__ __launch_bounds__(256) void finalize_kernel(
    const int* __restrict__ hist, const double* __restrict__ psse,
    float* __restrict__ outs) {
  int tid = threadIdx.x;
  double e = 0.0, s = 0.0;
  for (int k = tid; k < NLAT; k += 256) {
    int c = hist[k];
    if (c > 0) {
      float p = (float)c * (1.0f / 32768.0f);
      e += (double)(p * logf(p));
    }
  }
  for (int k = tid; k < BATCH / 4; k += 256) s += psse[k];
  #pragma unroll
  for (int off = 32; off; off >>= 1) {
    e += __shfl_xor(e, off, 64);
    s += __shfl_xor(s, off, 64);
  }
  __shared__ double pe[4], ps[4];
  int w = tid >> 6, l = tid & 63;
  if (l == 0) { pe[w] = e; ps[w] = s; }
  __syncthreads();
  if (tid == 0) {
    double H = -((pe[0] + pe[1]) + (pe[2] + pe[3]));
    double sse = (ps[0] + ps[1]) + (ps[2] + ps[3]);
    double qv = sse * (1.0 / ((double)BATCH * (double)DIM));
    float qf = (float)qv;
    float Hf = (float)H;
    float ent_loss = -Hf;
    float vq = qf + 0.25f * qf + 0.1f * ent_loss;
    outs[0] = vq;
    outs[1] = qf;
    outs[2] = qf;
    outs[3] = ent_loss;
    outs[4] = Hf;
  }
}

extern "C" void kernel_launch(void* const* d_in, const int* in_sizes, int n_in,
                              void* d_out, int out_size, void* d_ws, size_t ws_size,
                              hipStream_t stream) {
  const float* x  = (const float*)d_in[0];
  const float* cb = (const float*)d_in[1];

  float* out     = (float*)d_out;
  float* zq      = out;
  float* scalars = out + (size_t)BATCH * DIM;
  float* oidx    = scalars + 5;

  char* wsb = (char*)d_ws;
  ushort* cbhf  = (ushort*)(wsb + WS_CBH);
  float*  cbinv = (float*)(wsb + WS_CBINV);
  uint*   keys  = (uint*)(wsb + WS_KEYS);
  int*    hist  = (int*)(wsb + WS_HIST);
  // per-block SSE partials reuse the cbhf region (dead after vq_gemm)
  double* psse  = (double*)(wsb + WS_CBH);

  // fp16 fragment-major x scratch in the first 16 MB of the zq output
  ushort* xhf = (ushort*)d_out;

  prep1_kernel<<<1025, 256, 0, stream>>>(cb, cbinv, hist);
  prep2_kernel<<<1536, 256, 0, stream>>>(x, cb, cbinv,
                                         (uint4*)cbhf, (uint4*)xhf);
  vq_gemm_kernel<<<512, 256, 0, stream>>>((const char*)xhf,
                                          (const char*)cbhf, keys);
  rescore_kernel<<<BATCH / 4, 256, 0, stream>>>(x, cb, cbinv, keys,
                                                zq, oidx, hist, psse);
  finalize_kernel<<<1, 256, 0, stream>>>(hist, psse, scalars);
}